// Round 2
// baseline (319.471 us; speedup 1.0000x reference)
//
#include <hip/hip_runtime.h>
#include <math.h>

namespace {
constexpr int H = 800;
constexpr int W = 640;
constexpr int L = 19;
constexpr int B = 2;
constexpr int NC = B * L;                     // 38 (b,l) channels
constexpr int ROWS_PER_BLOCK = 8;
constexpr int W4 = W / 4;                     // 160 float4 per row
constexpr int V_PER_BLOCK = ROWS_PER_BLOCK * W4;  // 1280 float4 per block
constexpr float R1SQ = 41.0f * 41.0f;
constexpr float INV_R2 = 0.01f;
}

// One block = one (b,l) channel x 8 rows. Coalesced float4 logit reads for the
// BCE term (full channel); predX/predY read ONLY where the 4-px group can
// intersect the radius-41 disk (saves ~150 MB of the 233 MB input).
__global__ __launch_bounds__(256) void loss_partial(
    const float* __restrict__ fm, const float* __restrict__ lm,
    float* __restrict__ acc) {
  const int ch = blockIdx.x;          // 0..37
  const int b = ch / L;
  const int l = ch - b * L;
  const int i0 = blockIdx.y * ROWS_PER_BLOCK;

  // jnp.round == round-half-to-even == rintf under default rounding mode
  const float X = rintf(lm[2 * ch + 0] * (float)(H - 1));
  const float Y = rintf(lm[2 * ch + 1] * (float)(W - 1));

  const size_t chanStride = (size_t)H * W;
  const float4* lg4 = (const float4*)(fm + (size_t)(b * 3 * L + l) * chanStride);
  const float4* px4 = (const float4*)(fm + (size_t)(b * 3 * L + L + l) * chanStride);
  const float4* py4 = (const float4*)(fm + (size_t)(b * 3 * L + 2 * L + l) * chanStride);

  float bceS = 0.f, l1xS = 0.f, l1yS = 0.f, cntS = 0.f;

  const int tid = threadIdx.x;
#pragma unroll
  for (int it = 0; it < V_PER_BLOCK / 256; ++it) {   // exactly 5 iterations
    const int v = tid + it * 256;
    const int r = v / W4;
    const int c4 = v - r * W4;
    const int row = i0 + r;
    const int col = c4 * 4;

    const float4 lg = lg4[row * W4 + c4];

    const float dX = X - (float)row;
    const float dX2 = dX * dX;
    const bool rowIn = dX2 <= R1SQ;

    float xs[4] = {lg.x, lg.y, lg.z, lg.w};
    float dY[4];
#pragma unroll
    for (int k = 0; k < 4; ++k) dY[k] = Y - (float)(col + k);

    bool in[4];
    bool anyIn = false;
#pragma unroll
    for (int k = 0; k < 4; ++k) {
      in[k] = rowIn && (dX2 + dY[k] * dY[k] <= R1SQ);
      anyIn |= in[k];
    }

    float px[4] = {0.f, 0.f, 0.f, 0.f};
    float py[4] = {0.f, 0.f, 0.f, 0.f};
    if (anyIn) {
      const float4 a = px4[row * W4 + c4];
      const float4 bb = py4[row * W4 + c4];
      px[0] = a.x;  px[1] = a.y;  px[2] = a.z;  px[3] = a.w;
      py[0] = bb.x; py[1] = bb.y; py[2] = bb.z; py[3] = bb.w;
    }

#pragma unroll
    for (int k = 0; k < 4; ++k) {
      const float x = xs[k];
      // max(x,0) + softplus(-|x|)  (== stable log(1+e^x))
      const float sp = log1pf(__expf(-fabsf(x)));
      float base = fmaxf(x, 0.f) + sp;
      if (in[k]) {
        base -= x;                              // the -x*heat term
        cntS += 1.f;
        l1xS += fabsf(px[k] - dX * INV_R2);
        l1yS += fabsf(py[k] - dY[k] * INV_R2);
      }
      bceS += base;
    }
  }

  // block reduction: wave64 shuffle, then 4 wave partials via LDS
#pragma unroll
  for (int off = 32; off > 0; off >>= 1) {
    bceS += __shfl_down(bceS, off);
    l1xS += __shfl_down(l1xS, off);
    l1yS += __shfl_down(l1yS, off);
    cntS += __shfl_down(cntS, off);
  }
  __shared__ float4 wacc[4];
  const int wid = tid >> 6;
  if ((tid & 63) == 0) wacc[wid] = make_float4(bceS, l1xS, l1yS, cntS);
  __syncthreads();
  if (tid == 0) {
    float4 s = wacc[0];
#pragma unroll
    for (int wq = 1; wq < 4; ++wq) {
      s.x += wacc[wq].x; s.y += wacc[wq].y;
      s.z += wacc[wq].z; s.w += wacc[wq].w;
    }
    atomicAdd(&acc[4 * ch + 0], s.x);
    atomicAdd(&acc[4 * ch + 1], s.y);
    atomicAdd(&acc[4 * ch + 2], s.z);
    atomicAdd(&acc[4 * ch + 3], s.w);
  }
}

__global__ void finalize(const float* __restrict__ acc, float* __restrict__ out) {
  const int t = threadIdx.x;   // 64 threads, one wave
  float v = 0.f;
  if (t < NC) {
    const float bce = acc[4 * t + 0] * (1.0f / (float)(H * W));
    const float cnt = acc[4 * t + 3];
    v = 2.f * bce + acc[4 * t + 1] / cnt + acc[4 * t + 2] / cnt;
  }
#pragma unroll
  for (int off = 32; off > 0; off >>= 1) v += __shfl_down(v, off);
  if (t == 0) out[0] = v * (1.0f / (float)NC);
}

extern "C" void kernel_launch(void* const* d_in, const int* in_sizes, int n_in,
                              void* d_out, int out_size, void* d_ws, size_t ws_size,
                              hipStream_t stream) {
  const float* fm = (const float*)d_in[0];   // (2, 57, 800, 640) fp32
  const float* lm = (const float*)d_in[1];   // (2, 19, 2) fp32
  float* out = (float*)d_out;                // scalar fp32
  float* acc = (float*)d_ws;                 // 38 * 4 floats

  // ws is re-poisoned to 0xAA before every timed call — must re-zero each time
  hipMemsetAsync(d_ws, 0, NC * 4 * sizeof(float), stream);

  dim3 grid(NC, H / ROWS_PER_BLOCK);         // 38 x 100 blocks
  loss_partial<<<grid, 256, 0, stream>>>(fm, lm, acc);
  finalize<<<1, 64, 0, stream>>>(acc, out);
}

// Round 3
// 301.713 us; speedup vs baseline: 1.0589x; 1.0589x over previous
//
#include <hip/hip_runtime.h>
#include <math.h>

namespace {
constexpr int H = 800;
constexpr int W = 640;
constexpr int L = 19;
constexpr int B = 2;
constexpr int NC = B * L;                     // 38 (b,l) channels
constexpr int ROWS_PER_BLOCK = 8;
constexpr int NB = H / ROWS_PER_BLOCK;        // 100 row-blocks per channel
constexpr int W4 = W / 4;                     // 160 float4 per row
constexpr int V_PER_BLOCK = ROWS_PER_BLOCK * W4;  // 1280 float4 per block
constexpr float R1SQ = 41.0f * 41.0f;
constexpr float INV_R2 = 0.01f;
}

// One block = one (b,l) channel x 8 rows. Coalesced float4 logit reads for the
// BCE term (full channel); predX/predY read ONLY where the 4-px group can
// intersect the radius-41 disk. Writes one float4 partial per block to d_ws
// (no atomics, no zero-init needed -- every slot is overwritten).
__global__ __launch_bounds__(256) void loss_partial(
    const float* __restrict__ fm, const float* __restrict__ lm,
    float4* __restrict__ part) {
  const int ch = blockIdx.x;          // 0..37
  const int b = ch / L;
  const int l = ch - b * L;
  const int i0 = blockIdx.y * ROWS_PER_BLOCK;

  // jnp.round == round-half-to-even == rintf under default rounding mode
  const float X = rintf(lm[2 * ch + 0] * (float)(H - 1));
  const float Y = rintf(lm[2 * ch + 1] * (float)(W - 1));

  const size_t chanStride = (size_t)H * W;
  const float4* lg4 = (const float4*)(fm + (size_t)(b * 3 * L + l) * chanStride);
  const float4* px4 = (const float4*)(fm + (size_t)(b * 3 * L + L + l) * chanStride);
  const float4* py4 = (const float4*)(fm + (size_t)(b * 3 * L + 2 * L + l) * chanStride);

  float bceS = 0.f, l1xS = 0.f, l1yS = 0.f, cntS = 0.f;

  const int tid = threadIdx.x;
#pragma unroll
  for (int it = 0; it < V_PER_BLOCK / 256; ++it) {   // exactly 5 iterations
    const int v = tid + it * 256;
    const int r = v / W4;
    const int c4 = v - r * W4;
    const int row = i0 + r;
    const int col = c4 * 4;

    const float4 lg = lg4[row * W4 + c4];

    const float dX = X - (float)row;
    const float dX2 = dX * dX;
    const bool rowIn = dX2 <= R1SQ;

    float xs[4] = {lg.x, lg.y, lg.z, lg.w};
    float dY[4];
#pragma unroll
    for (int k = 0; k < 4; ++k) dY[k] = Y - (float)(col + k);

    bool in[4];
    bool anyIn = false;
#pragma unroll
    for (int k = 0; k < 4; ++k) {
      in[k] = rowIn && (dX2 + dY[k] * dY[k] <= R1SQ);
      anyIn |= in[k];
    }

    float px[4] = {0.f, 0.f, 0.f, 0.f};
    float py[4] = {0.f, 0.f, 0.f, 0.f};
    if (anyIn) {
      const float4 a = px4[row * W4 + c4];
      const float4 bb = py4[row * W4 + c4];
      px[0] = a.x;  px[1] = a.y;  px[2] = a.z;  px[3] = a.w;
      py[0] = bb.x; py[1] = bb.y; py[2] = bb.z; py[3] = bb.w;
    }

#pragma unroll
    for (int k = 0; k < 4; ++k) {
      const float x = xs[k];
      // max(x,0) + softplus(-|x|); stable since exp arg <= 0.
      // __expf/__logf are v_exp_f32/v_log_f32 -- ~1e-7 rel err, vastly under
      // the 6.5e-2 output threshold.
      const float sp = __logf(1.0f + __expf(-fabsf(x)));
      float base = fmaxf(x, 0.f) + sp;
      if (in[k]) {
        base -= x;                              // the -x*heat term
        cntS += 1.f;
        l1xS += fabsf(px[k] - dX * INV_R2);
        l1yS += fabsf(py[k] - dY[k] * INV_R2);
      }
      bceS += base;
    }
  }

  // block reduction: wave64 shuffle, then 4 wave partials via LDS
#pragma unroll
  for (int off = 32; off > 0; off >>= 1) {
    bceS += __shfl_down(bceS, off);
    l1xS += __shfl_down(l1xS, off);
    l1yS += __shfl_down(l1yS, off);
    cntS += __shfl_down(cntS, off);
  }
  __shared__ float4 wacc[4];
  const int wid = tid >> 6;
  if ((tid & 63) == 0) wacc[wid] = make_float4(bceS, l1xS, l1yS, cntS);
  __syncthreads();
  if (tid == 0) {
    float4 s = wacc[0];
#pragma unroll
    for (int wq = 1; wq < 4; ++wq) {
      s.x += wacc[wq].x; s.y += wacc[wq].y;
      s.z += wacc[wq].z; s.w += wacc[wq].w;
    }
    part[ch * NB + blockIdx.y] = s;             // unique slot, no atomic
  }
}

// Reduce 38*100 float4 partials -> scalar. Single 256-thread block.
__global__ __launch_bounds__(256) void finalize(
    const float4* __restrict__ part, float* __restrict__ out) {
  __shared__ float4 chAcc[NC];
  __shared__ float chLoss[NC];
  const int tid = threadIdx.x;
  if (tid < NC) chAcc[tid] = make_float4(0.f, 0.f, 0.f, 0.f);
  __syncthreads();
  for (int f = tid; f < NC * NB; f += 256) {
    const int c = f / NB;
    const float4 p = part[f];
    atomicAdd(&chAcc[c].x, p.x);
    atomicAdd(&chAcc[c].y, p.y);
    atomicAdd(&chAcc[c].z, p.z);
    atomicAdd(&chAcc[c].w, p.w);
  }
  __syncthreads();
  if (tid < NC) {
    const float4 s = chAcc[tid];
    chLoss[tid] = 2.f * s.x * (1.0f / (float)(H * W)) + (s.y + s.z) / s.w;
  }
  __syncthreads();
  if (tid == 0) {
    float v = 0.f;
    for (int c = 0; c < NC; ++c) v += chLoss[c];
    out[0] = v * (1.0f / (float)NC);
  }
}

extern "C" void kernel_launch(void* const* d_in, const int* in_sizes, int n_in,
                              void* d_out, int out_size, void* d_ws, size_t ws_size,
                              hipStream_t stream) {
  const float* fm = (const float*)d_in[0];   // (2, 57, 800, 640) fp32
  const float* lm = (const float*)d_in[1];   // (2, 19, 2) fp32
  float* out = (float*)d_out;                // scalar fp32
  float4* part = (float4*)d_ws;              // 38*100 float4 partials (60.8 KB)

  dim3 grid(NC, NB);                         // 38 x 100 blocks
  loss_partial<<<grid, 256, 0, stream>>>(fm, lm, part);
  finalize<<<1, 256, 0, stream>>>(part, out);
}